// Round 8
// baseline (1475.859 us; speedup 1.0000x reference)
//
#include <hip/hip_runtime.h>

// WasserIndexGen: Wasserstein barycenter Sinkhorn (N=4096, NBB=64, <=30 iters).
// Round-8: ONE PERSISTENT KERNEL for all 30 iterations (round-7 showed
// per-dispatch overhead dominating: ~60 serialized graph nodes at ~19us
// each while the GEMM math itself is ~2-4us). Grid = 256 blocks = 1/CU
// (co-resident => manual grid barrier is safe), 512 threads (8 waves).
// Two-level ticket barrier (8 group counters -> top epoch), 2 barriers/iter;
// loop control recomputed redundantly per block (no control barrier).
// GEMM core: round-7's validated fragment addressing (absmax 0.0), pipeline
// deepened 3->5. Block b owns rows [16b,16b+16) of both Cu and Va stripes;
// same rows every iteration => L2/XCD affinity for its C/CT stripes.
// Dispatches: k_setup, k_cgen, k_persist (3 total; k_final folded in).
//
// ws (~67 MB): Cbf bf16[4096][4096], CTbf bf16[4096][4096], uT/rT bf16
// [64][4096], u/v f32[4096][64], yh f32[4096], Spart f32[256*4],
// Sctl int[512] = {bar1[256], bar2, pad, badf[30]}.

typedef __attribute__((ext_vector_type(8))) short bf16x8;
typedef __attribute__((ext_vector_type(4))) float f32x4;

constexpr int NV    = 4096;
constexpr int NBB_  = 64;
constexpr int ITERS = 30;

__device__ __forceinline__ bool finitef(float x) {
  return __builtin_fabsf(x) <= 3.402823466e38f;  // false for NaN/inf
}

__device__ __forceinline__ unsigned short f2bf(float x) {  // RNE f32->bf16
  unsigned int u = __builtin_bit_cast(unsigned int, x);
  return (unsigned short)((u + 0x7fffu + ((u >> 16) & 1u)) >> 16);
}

// Two-level grid barrier, monotone epochs. jb = 1-based barrier index.
// Release fence before arrive, acquire fence after observing release; this
// fence+atomic pattern is the one validated cross-XCD in rounds 4-7.
__device__ __forceinline__ void gbar(int* __restrict__ bar1,
                                     int* __restrict__ bar2, int jb) {
  __syncthreads();
  if (threadIdx.x == 0) {
    __threadfence();
    const int g = blockIdx.x & 7;
    const int n = atomicAdd(&bar1[g * 32], 1);    // group counters 128B apart
    if (n == 32 * jb - 1) atomicAdd(bar2, 1);     // last of group arrives top
    while (__hip_atomic_load(bar2, __ATOMIC_RELAXED, __HIP_MEMORY_SCOPE_AGENT) <
           8 * jb)
      __builtin_amdgcn_s_sleep(2);
    __threadfence();
  }
  __syncthreads();
}

// ---------------- setup: iterates + control/barrier state -------------------
__global__ void k_setup(float* __restrict__ u, float* __restrict__ v,
                        unsigned short* __restrict__ uT, float* __restrict__ yh,
                        int* __restrict__ Sctl) {
  const int gid = blockIdx.x * 256 + threadIdx.x;  // 16384 threads
  for (int i = gid; i < NV * NBB_; i += 16384) {
    u[i] = 1.0f; v[i] = 1.0f; uT[i] = 0x3F80;      // bf16(1.0)
  }
  for (int i = gid; i < NV; i += 16384) yh[i] = 0.0f;
  if (gid < 512) Sctl[gid] = 0;                    // bar1, bar2, badf
}

// ---------------- Cbf = bf16(exp(-M/reg)), CTbf = Cbf^T ---------------------
__global__ void k_cgen(const float* __restrict__ M, const float* __restrict__ regp,
                       unsigned short* __restrict__ Cb,
                       unsigned short* __restrict__ CTb) {
  __shared__ float tile[64][65];
  const int jb = (blockIdx.x & 63) * 64;
  const int ib = (blockIdx.x >> 6) * 64;
  const float ninv = -1.0f / regp[0];
  const int t = threadIdx.x;
#pragma unroll
  for (int s = 0; s < 4; ++s) {
    const int l = s * 256 + t;
    const int r = l >> 4, c4 = l & 15;
    const float4 m4 = *(const float4*)&M[(size_t)(ib + r) * NV + jb + c4 * 4];
    float4 e4;
    e4.x = __expf(m4.x * ninv);
    e4.y = __expf(m4.y * ninv);
    e4.z = __expf(m4.z * ninv);
    e4.w = __expf(m4.w * ninv);
    ushort4 o;
    o.x = f2bf(e4.x); o.y = f2bf(e4.y); o.z = f2bf(e4.z); o.w = f2bf(e4.w);
    *(ushort4*)&Cb[(size_t)(ib + r) * NV + jb + c4 * 4] = o;
    *(float4*)&tile[r][c4 * 4] = e4;
  }
  __syncthreads();
#pragma unroll
  for (int s = 0; s < 4; ++s) {
    const int l = s * 256 + t;
    const int r = l >> 4, c4 = l & 15;
    ushort4 o;
    o.x = f2bf(tile[c4 * 4 + 0][r]);
    o.y = f2bf(tile[c4 * 4 + 1][r]);
    o.z = f2bf(tile[c4 * 4 + 2][r]);
    o.w = f2bf(tile[c4 * 4 + 3][r]);
    *(ushort4*)&CTb[(size_t)(jb + r) * NV + ib + c4 * 4] = o;
  }
}

// GEMM core: block owns 16 output rows, wave w owns k-slice [w*512,+512),
// computes all 4 col-tiles (A read once). 5-deep register pipeline, all
// indices static after unroll. Fragment addressing validated (r4/r7):
//   A lane(lr,lg): row=lr, k=lg*8+j; B: col=lr; D: col=ct*16+lr, row=lg*4+q.
#define GEMM_CORE(Abase, Bbase)                                                \
  {                                                                            \
    const unsigned short* Ap = (Abase) + (size_t)(R + lr) * NV + w * 512 + lg * 8; \
    const unsigned short* Bp = (Bbase) + (size_t)lr * NV + w * 512 + lg * 8;   \
    f32x4 acc[4] = {};                                                         \
    bf16x8 abuf[5];                                                            \
    bf16x8 bbuf[5][4];                                                         \
    _Pragma("unroll")                                                          \
    for (int p = 0; p < 5; ++p) {                                              \
      abuf[p] = *(const bf16x8*)(Ap + 32 * p);                                 \
      _Pragma("unroll")                                                        \
      for (int ct = 0; ct < 4; ++ct)                                           \
        bbuf[p][ct] = *(const bf16x8*)(Bp + (size_t)ct * 16 * NV + 32 * p);    \
    }                                                                          \
    _Pragma("unroll")                                                          \
    for (int i = 0; i < 16; ++i) {                                             \
      const int sl = i % 5;                                                    \
      _Pragma("unroll")                                                        \
      for (int ct = 0; ct < 4; ++ct)                                           \
        acc[ct] = __builtin_amdgcn_mfma_f32_16x16x32_bf16(abuf[sl],            \
                                                          bbuf[sl][ct],        \
                                                          acc[ct], 0, 0, 0);   \
      if (i + 5 < 16) {                                                        \
        abuf[sl] = *(const bf16x8*)(Ap + 32 * (i + 5));                        \
        _Pragma("unroll")                                                      \
        for (int ct = 0; ct < 4; ++ct)                                         \
          bbuf[sl][ct] =                                                       \
              *(const bf16x8*)(Bp + (size_t)ct * 16 * NV + 32 * (i + 5));      \
      }                                                                        \
    }                                                                          \
    _Pragma("unroll")                                                          \
    for (int ct = 0; ct < 4; ++ct) red4[w][ct][lane] = acc[ct];                \
  }

// ---------------- persistent kernel: all 30 Sinkhorn iterations -------------
__global__ __launch_bounds__(512, 2) void k_persist(
    const unsigned short* __restrict__ Cb, const unsigned short* __restrict__ CTb,
    const float* __restrict__ b, const float* __restrict__ lbd,
    const float* __restrict__ a, float* __restrict__ u, float* __restrict__ v,
    unsigned short* __restrict__ uT, unsigned short* __restrict__ rT,
    float* __restrict__ yh, float* __restrict__ Spart, int* __restrict__ bar1,
    int* __restrict__ bar2, int* __restrict__ badf, float* __restrict__ out) {
  __shared__ f32x4 red4[8][4][64];  // 32 KB
  __shared__ float yred[4][16];
  __shared__ float yhl[16];
  __shared__ float wred[4][4];
  __shared__ float cred[4][4];
  __shared__ float fred[8];
  __shared__ float serr;
  __shared__ int   sbad;
  const int R = blockIdx.x * 16;
  const int t = threadIdx.x, w = t >> 6, lane = t & 63;
  const int lr = lane & 15, lg = lane >> 4;
  float err = 1.0f;
  int cpt = 0, nb = 0;
  bool broke = false;

  for (int it = 0; it < ITERS; ++it) {
    // ---------- phase A: Cu rows = C[R..R+16) @ u ; r = b / Cu ----------
    GEMM_CORE(Cb, uT)
    __syncthreads();
    if (w < 4) {
      f32x4 cu = red4[0][w][lane];
#pragma unroll
      for (int j = 1; j < 8; ++j) cu += red4[j][w][lane];
      bool badl = false;
      float rq[4];
#pragma unroll
      for (int q = 0; q < 4; ++q) {
        const float cuq = cu[q];
        const float bq  = b[(R + lg * 4 + q) * NBB_ + w * 16 + lr];
        badl |= (cuq == 0.0f);
        rq[q] = bq / cuq;
      }
      ushort4 rr;
      rr.x = f2bf(rq[0]); rr.y = f2bf(rq[1]);
      rr.z = f2bf(rq[2]); rr.w = f2bf(rq[3]);
      *(ushort4*)&rT[(size_t)(w * 16 + lr) * NV + R + lg * 4] = rr;
      if (badl) atomicOr(&badf[it], 1);
    }
    ++nb; gbar(bar1, bar2, nb);

    // ---------- phase B: Va rows = C^T[R..R+16) @ r ; rowwise ----------
    GEMM_CORE(CTb, rT)
    __syncthreads();
    f32x4 vv = {0.f, 0.f, 0.f, 0.f};
    if (w < 4) {
      vv = red4[0][w][lane];
#pragma unroll
      for (int j = 1; j < 8; ++j) vv += red4[j][w][lane];
      const float lb = lbd[w * 16 + lr];
      float p[4];
#pragma unroll
      for (int q = 0; q < 4; ++q) p[q] = lb * __logf(vv[q]);
#pragma unroll
      for (int o = 1; o < 16; o <<= 1) {
#pragma unroll
        for (int q = 0; q < 4; ++q) p[q] += __shfl_xor(p[q], o);
      }
      if (lr == 0) {
#pragma unroll
        for (int q = 0; q < 4; ++q) yred[w][lg * 4 + q] = p[q];
      }
    }
    __syncthreads();
    if (t < 16) {
      const float s   = yred[0][t] + yred[1][t] + yred[2][t] + yred[3][t];
      const float yhv = __expf(s);  // prod_j v^lbd_j
      yhl[t] = yhv;
      if (!finitef(yhv)) atomicOr(&badf[it], 1);
    }
    __syncthreads();
    if (w < 4) {
      float s0 = 0.f, s1 = 0.f, s2 = 0.f, s3 = 0.f;
      bool badl = false;
      float un4[4];
#pragma unroll
      for (int q = 0; q < 4; ++q) {
        const int   row = lg * 4 + q;
        const float yhv = yhl[row];
        const float un  = yhv / vv[q];
        un4[q] = un;
        const int idx = (R + row) * NBB_ + w * 16 + lr;
        const float uo = u[idx], vo = v[idx];
        u[idx] = un;
        v[idx] = vv[q];
        const float du = un - uo, dv = vv[q] - vo;
        s0 += du * du; s1 += un * un; s2 += dv * dv; s3 += vv[q] * vv[q];
        badl |= !(finitef(un) && finitef(vv[q]));
      }
      ushort4 uu;
      uu.x = f2bf(un4[0]); uu.y = f2bf(un4[1]);
      uu.z = f2bf(un4[2]); uu.w = f2bf(un4[3]);
      *(ushort4*)&uT[(size_t)(w * 16 + lr) * NV + R + lg * 4] = uu;
      if (badl) atomicOr(&badf[it], 1);
#pragma unroll
      for (int o = 1; o < 64; o <<= 1) {
        s0 += __shfl_xor(s0, o); s1 += __shfl_xor(s1, o);
        s2 += __shfl_xor(s2, o); s3 += __shfl_xor(s3, o);
      }
      if (lane == 0) {
        wred[w][0] = s0; wred[w][1] = s1; wred[w][2] = s2; wred[w][3] = s3;
      }
    }
    __syncthreads();
    if (t == 0) {
#pragma unroll
      for (int c = 0; c < 4; ++c)
        Spart[blockIdx.x * 4 + c] =
            wred[0][c] + wred[1][c] + wred[2][c] + wred[3][c];
    }
    ++nb; gbar(bar1, bar2, nb);

    // ---------- control: every block redundantly, identical result ----------
    if (t == 0)
      sbad = __hip_atomic_load(&badf[it], __ATOMIC_RELAXED,
                               __HIP_MEMORY_SCOPE_AGENT);
    __syncthreads();
    if (sbad == 0) {
      if (cpt % 10 == 0) {
        // block-wide reduce of Spart[256][4]
        float4 sp = make_float4(0.f, 0.f, 0.f, 0.f);
        if (t < 256) sp = ((const float4*)Spart)[t];
        float s0 = sp.x, s1 = sp.y, s2 = sp.z, s3 = sp.w;
#pragma unroll
        for (int o = 1; o < 64; o <<= 1) {
          s0 += __shfl_xor(s0, o); s1 += __shfl_xor(s1, o);
          s2 += __shfl_xor(s2, o); s3 += __shfl_xor(s3, o);
        }
        if (lane == 0 && w < 4) {
          cred[w][0] = s0; cred[w][1] = s1; cred[w][2] = s2; cred[w][3] = s3;
        }
        __syncthreads();
        if (t == 0) {
          const float q0 = cred[0][0] + cred[1][0] + cred[2][0] + cred[3][0];
          const float q1 = cred[0][1] + cred[1][1] + cred[2][1] + cred[3][1];
          const float q2 = cred[0][2] + cred[1][2] + cred[2][2] + cred[3][2];
          const float q3 = cred[0][3] + cred[1][3] + cred[2][3] + cred[3][3];
          serr = q0 / q1 + q2 / q3;  // err = lhs + rhs
        }
        __syncthreads();
        err = serr;
      }
      ++cpt;
      if (t < 16) yh[R + t] = yhl[t];  // commit this block's yhat rows
    } else {
      broke = true;
    }
    if (broke || !(err > 1e-9f) || cpt >= ITERS) break;
  }

  // ---------- final: out = sum((yhat - a)^2), block 0 ----------
  ++nb; gbar(bar1, bar2, nb);
  if (blockIdx.x == 0) {
    float s = 0.0f;
    for (int i = t; i < NV; i += 512) {
      const float d = yh[i] - a[i];
      s = fmaf(d, d, s);
    }
#pragma unroll
    for (int o = 1; o < 64; o <<= 1) s += __shfl_xor(s, o);
    if (lane == 0) fred[w] = s;
    __syncthreads();
    if (t == 0) {
      float q = 0.0f;
#pragma unroll
      for (int i = 0; i < 8; ++i) q += fred[i];
      out[0] = q;
    }
  }
}

extern "C" void kernel_launch(void* const* d_in, const int* in_sizes, int n_in,
                              void* d_out, int out_size, void* d_ws, size_t ws_size,
                              hipStream_t stream) {
  const float* a   = (const float*)d_in[0];
  const float* M   = (const float*)d_in[1];
  const float* b   = (const float*)d_in[2];
  const float* lbd = (const float*)d_in[3];
  const float* reg = (const float*)d_in[4];
  float* out = (float*)d_out;

  char* wsb = (char*)d_ws;
  size_t off = 0;
  auto alloc = [&](size_t bytes) -> void* {
    void* p = wsb + off;
    off += (bytes + 255) & ~(size_t)255;
    return p;
  };
  unsigned short* Cbf   = (unsigned short*)alloc(2 * (size_t)NV * NV);
  unsigned short* CTbf  = (unsigned short*)alloc(2 * (size_t)NV * NV);
  unsigned short* uT    = (unsigned short*)alloc(2 * (size_t)NV * NBB_);
  unsigned short* rT    = (unsigned short*)alloc(2 * (size_t)NV * NBB_);
  float*          u     = (float*)alloc(sizeof(float) * (size_t)NV * NBB_);
  float*          v     = (float*)alloc(sizeof(float) * (size_t)NV * NBB_);
  float*          yh    = (float*)alloc(sizeof(float) * NV);
  float*          Spart = (float*)alloc(sizeof(float) * 256 * 4);
  int*            Sctl  = (int*)alloc(sizeof(int) * 512);
  int* bar1 = Sctl;          // [0..255], group counters at stride 32
  int* bar2 = Sctl + 256;    // top epoch
  int* badf = Sctl + 288;    // per-iteration bad flags [30]

  k_setup<<<dim3(64), dim3(256), 0, stream>>>(u, v, uT, yh, Sctl);
  k_cgen<<<dim3(4096), dim3(256), 0, stream>>>(M, reg, Cbf, CTbf);
  k_persist<<<dim3(256), dim3(512), 0, stream>>>(Cbf, CTbf, b, lbd, a, u, v,
                                                 uT, rT, yh, Spart, bar1, bar2,
                                                 badf, out);
}